// Round 18
// baseline (73.200 us; speedup 1.0000x reference)
//
#include <hip/hip_runtime.h>

typedef float f32x4 __attribute__((ext_vector_type(4)));
typedef __bf16 bf16x8 __attribute__((ext_vector_type(8)));
typedef unsigned short u16x4 __attribute__((ext_vector_type(4)));
typedef unsigned short u16x8 __attribute__((ext_vector_type(8)));

__device__ __forceinline__ unsigned short f2b(float f){
  return __builtin_bit_cast(unsigned short, (__bf16)f);
}
__device__ __forceinline__ float b2f(unsigned short u){
  union { unsigned x; float f; } v; v.x = ((unsigned)u) << 16; return v.f;
}
__device__ __forceinline__ void mfma3(f32x4& acc, bf16x8 ah, bf16x8 al, bf16x8 bh, bf16x8 bl){
  acc = __builtin_amdgcn_mfma_f32_16x16x32_bf16(ah, bh, acc, 0, 0, 0);
  acc = __builtin_amdgcn_mfma_f32_16x16x32_bf16(ah, bl, acc, 0, 0, 0);
  acc = __builtin_amdgcn_mfma_f32_16x16x32_bf16(al, bh, acc, 0, 0, 0);
}
__device__ __forceinline__ void gload16(const void* g, void* l){
  __builtin_amdgcn_global_load_lds((const __attribute__((address_space(1))) void*)g,
                                   (__attribute__((address_space(3))) void*)l, 16, 0, 0);
}

// Fully-parallel 1-granule (8192 elems) f32->bf16 conversion (R15-proven fn).
__device__ __forceinline__ void conv_gran(const float* __restrict__ X,
                                          unsigned short* __restrict__ Xb,
                                          int g, int tid){
  const float* src = X + (size_t)g * 8192;
  unsigned short* dst = Xb + (size_t)g * 8192;
  f32x4 v[8];
  #pragma unroll
  for (int it = 0; it < 8; ++it)
    v[it] = *reinterpret_cast<const f32x4*>(src + (tid + it*256)*4);
  #pragma unroll
  for (int it = 0; it < 8; ++it){
    u16x4 h;
    #pragma unroll
    for (int e = 0; e < 4; ++e) h[e] = f2b(v[it][e]);
    *reinterpret_cast<u16x4*>(dst + (tid + it*256)*4) = h;
  }
}

// ---------- chain staging loaders/writers (proven rounds 3-17) ----------
template<bool ATR>
__device__ __forceinline__ void loadA(const float* __restrict__ A, int i0, int k0,
                                      int tid, float* aR){
  if (ATR){
    int r32 = tid & 31, kg = tid >> 5;
    #pragma unroll
    for (int q = 0; q < 8; ++q)
      aR[q] = -A[(k0 + kg*8 + q)*512 + i0 + r32];
  } else {
    #pragma unroll
    for (int j = 0; j < 2; ++j){
      int p = tid + j*256;
      int row = p >> 4, kq = p & 15;
      f32x4 v = *reinterpret_cast<const f32x4*>(A + (i0+row)*512 + k0 + kq*4);
      #pragma unroll
      for (int e = 0; e < 4; ++e) aR[j*4+e] = v[e];
    }
  }
}
template<bool ATR>
__device__ __forceinline__ void writeA(const float* aR, int tid,
                                       unsigned short* Ah, unsigned short* Al){
  if (ATR){
    int r32 = tid & 31, kg = tid >> 5;
    #pragma unroll
    for (int q4 = 0; q4 < 2; ++q4){
      u16x4 hi, lo;
      #pragma unroll
      for (int e = 0; e < 4; ++e){
        float f = aR[q4*4+e];
        unsigned short h = f2b(f);
        hi[e] = h; lo[e] = f2b(f - b2f(h));
      }
      int off = r32*128 + (((kg*8 + q4*4)*2) ^ ((r32 & 7) << 4));
      *reinterpret_cast<u16x4*>((char*)Ah + off) = hi;
      *reinterpret_cast<u16x4*>((char*)Al + off) = lo;
    }
  } else {
    #pragma unroll
    for (int j = 0; j < 2; ++j){
      int p = tid + j*256;
      int row = p >> 4, kq = p & 15;
      u16x4 hi, lo;
      #pragma unroll
      for (int e = 0; e < 4; ++e){
        float f = aR[j*4+e];
        unsigned short h = f2b(f);
        hi[e] = h; lo[e] = f2b(f - b2f(h));
      }
      int off = row*128 + ((kq*8) ^ ((row & 7) << 4));
      *reinterpret_cast<u16x4*>((char*)Ah + off) = hi;
      *reinterpret_cast<u16x4*>((char*)Al + off) = lo;
    }
  }
}
template<bool BROWM>
__device__ __forceinline__ void loadB(const float* __restrict__ B, int j0, int k0,
                                      int sb, int tid, float* bR){
  if (BROWM){
    #pragma unroll
    for (int j = 0; j < 4; ++j){
      int p = tid + j*256;
      int n = p >> 4, kq = p & 15;
      f32x4 v = *reinterpret_cast<const f32x4*>(B + (j0+n)*512 + k0 + kq*4);
      #pragma unroll
      for (int e = 0; e < 4; ++e) bR[j*4+e] = -v[e];
    }
  } else {
    int n = tid & 63, kg = tid >> 6;
    #pragma unroll
    for (int q = 0; q < 16; ++q)
      bR[q] = B[(k0 + kg*16 + q)*sb + j0 + n];
  }
}
template<bool BROWM>
__device__ __forceinline__ void writeB(const float* bR, int tid,
                                       unsigned short* Bh, unsigned short* Bl){
  if (BROWM){
    #pragma unroll
    for (int j = 0; j < 4; ++j){
      int p = tid + j*256;
      int n = p >> 4, kq = p & 15;
      u16x4 hi, lo;
      #pragma unroll
      for (int e = 0; e < 4; ++e){
        float f = bR[j*4+e];
        unsigned short h = f2b(f);
        hi[e] = h; lo[e] = f2b(f - b2f(h));
      }
      int off = n*128 + ((kq*8) ^ ((n & 7) << 4));
      *reinterpret_cast<u16x4*>((char*)Bh + off) = hi;
      *reinterpret_cast<u16x4*>((char*)Bl + off) = lo;
    }
  } else {
    int n = tid & 63, kg = tid >> 6;
    #pragma unroll
    for (int q4 = 0; q4 < 4; ++q4){
      u16x4 hi, lo;
      #pragma unroll
      for (int e = 0; e < 4; ++e){
        float f = bR[q4*4+e];
        unsigned short h = f2b(f);
        hi[e] = h; lo[e] = f2b(f - b2f(h));
      }
      int off = n*128 + (((kg*16 + q4*4)*2) ^ ((n & 7) << 4));
      *reinterpret_cast<u16x4*>((char*)Bh + off) = hi;
      *reinterpret_cast<u16x4*>((char*)Bl + off) = lo;
    }
  }
}

// One 32x64 tile of C = [D +] A*B over K=512, split-bf16, 3-deep reg pipeline.
template<bool ATR, bool BROWM, bool HASD, bool BFOUT>
__device__ __forceinline__ void gtile(
    const float* __restrict__ A, const float* __restrict__ B,
    const float* __restrict__ D, float* __restrict__ Cf,
    unsigned short* __restrict__ Cb, int i0, int j0, int sb, int so,
    unsigned short* Ah, unsigned short* Al,
    unsigned short* Bh, unsigned short* Bl, int tid)
{
  int lane = tid & 63, wave = tid >> 6;
  int wm = wave >> 1, wn = wave & 1;
  f32x4 acc[2] = {};
  float aR0[8], bR0[16], aR1[8], bR1[16];
  loadA<ATR>(A, i0, 0, tid, aR0);
  loadB<BROWM>(B, j0, 0, sb, tid, bR0);
  loadA<ATR>(A, i0, 64, tid, aR1);
  loadB<BROWM>(B, j0, 64, sb, tid, bR1);

#define CHAIN_MFMA_PHASE                                                   \
    { _Pragma("unroll")                                                    \
      for (int kk = 0; kk < 2; ++kk){                                      \
        int kb = (kk*32 + (lane >> 4)*8) * 2;                              \
        int arow = wm*16 + (lane & 15);                                    \
        int aoff = arow*128 + (kb ^ ((arow & 7) << 4));                    \
        bf16x8 ah = *reinterpret_cast<const bf16x8*>((char*)Ah + aoff);    \
        bf16x8 al = *reinterpret_cast<const bf16x8*>((char*)Al + aoff);    \
        _Pragma("unroll")                                                  \
        for (int n = 0; n < 2; ++n){                                       \
          int brow = wn*32 + n*16 + (lane & 15);                           \
          int boff = brow*128 + (kb ^ ((brow & 7) << 4));                  \
          bf16x8 bh = *reinterpret_cast<const bf16x8*>((char*)Bh + boff);  \
          bf16x8 bl = *reinterpret_cast<const bf16x8*>((char*)Bl + boff);  \
          mfma3(acc[n], ah, al, bh, bl);                                   \
        }                                                                  \
      } }

  #pragma unroll 1
  for (int k0 = 0; k0 < 512; k0 += 128){
    writeA<ATR>(aR0, tid, Ah, Al);
    writeB<BROWM>(bR0, tid, Bh, Bl);
    __syncthreads();
    if (k0 + 128 < 512){
      loadA<ATR>(A, i0, k0 + 128, tid, aR0);
      loadB<BROWM>(B, j0, k0 + 128, sb, tid, bR0);
    }
    CHAIN_MFMA_PHASE
    __syncthreads();
    writeA<ATR>(aR1, tid, Ah, Al);
    writeB<BROWM>(bR1, tid, Bh, Bl);
    __syncthreads();
    if (k0 + 192 < 512){
      loadA<ATR>(A, i0, k0 + 192, tid, aR1);
      loadB<BROWM>(B, j0, k0 + 192, sb, tid, bR1);
    }
    CHAIN_MFMA_PHASE
    __syncthreads();
  }
#undef CHAIN_MFMA_PHASE

  #pragma unroll
  for (int n = 0; n < 2; ++n)
    #pragma unroll
    for (int r = 0; r < 4; ++r){
      int i = i0 + wm*16 + (lane >> 4)*4 + r;
      int j = j0 + wn*32 + n*16 + (lane & 15);
      float v = acc[n][r];
      if (HASD) v += D[i*so + j];
      if (BFOUT) Cb[i*so + j] = f2b(v);
      else       Cf[i*so + j] = v;
    }
}

// Doubling step; nconv>0 (step 1 only): grid-stride conversion of ALL X
// granules after the tile work — one-time BW cost, no chain amplification.
__global__ __launch_bounds__(256, 2) void k_step(
    const float* __restrict__ Q, const float* __restrict__ R,
    float* __restrict__ Qout, float* __restrict__ Rout,
    unsigned short* __restrict__ Tout,
    const float* __restrict__ X, unsigned short* __restrict__ Xb,
    int first, int last, int nconv)
{
  __shared__ unsigned short Ah[32*64], Al[32*64], Bh[64*64], Bl[64*64];
  int tid = threadIdx.x, bid = blockIdx.x;
  if (bid < 256){
    int i0 = (bid >> 4) * 32, j0 = (bid & 15) * 64;
    if (last)
      gtile<false,false,true ,true >(Q, R, R, nullptr, Tout, i0, j0, 1024, 1024, Ah,Al,Bh,Bl, tid);
    else if (first)
      gtile<true ,false,true ,false>(Q, R, R, Rout, nullptr, i0, j0, 1024, 1024, Ah,Al,Bh,Bl, tid);
    else
      gtile<false,false,true ,false>(Q, R, R, Rout, nullptr, i0, j0, 1024, 1024, Ah,Al,Bh,Bl, tid);
  } else {
    int t = bid - 256;
    int i0 = (t >> 3) * 32, j0 = (t & 7) * 64;
    if (first)
      gtile<true ,true ,false,false>(Q, Q, nullptr, Qout, nullptr, i0, j0, 512, 512, Ah,Al,Bh,Bl, tid);
    else
      gtile<false,false,false,false>(Q, Q, nullptr, Qout, nullptr, i0, j0, 512, 512, Ah,Al,Bh,Bl, tid);
  }
  int nb = (int)gridDim.x;
  for (int g = bid; g < nconv; g += nb)
    conv_gran(X, Xb, g, tid);
}

// Y[16384][512] = Xb[16384][1024](bf16) * Tt^T.
// R9 structure (gload_lds + both-sides XOR swizzle + dbuf + counted vmcnt)
// with BM=64: SAME per-tile density (16 MFMA : 12 ds_read per wave), but
// grid 1024 and LDS 48KB -> 3 blocks/CU (vs gemm9's grid-capped 2/CU).
__global__ __launch_bounds__(256, 3) void k_gemm18(const unsigned short* __restrict__ Xb,
                                                   const unsigned short* __restrict__ Tt,
                                                   float* __restrict__ Y)
{
  __shared__ unsigned short As_[2][64*64];    // 2 x 8 KB
  __shared__ unsigned short Bs_[2][128*64];   // 2 x 16 KB
  int tid = threadIdx.x;
  int lane = tid & 63, wave = tid >> 6;
  int wm = wave >> 1, wn = wave & 1;          // 2 (m) x 2 (n), per-wave 32x64
  int bid = blockIdx.x;
  int chunk = bid & 7, t = bid >> 3;          // 8 XCD chunks x 128 blocks
  int m0 = (chunk*32 + (t >> 2)) * 64;        // 32 m-panels per chunk
  int n0 = (t & 3) * 128;                     // n fastest: Xb panel L2 reuse

  int lrow = lane >> 3;                       // row within 8-row stripe
  int lg   = (lane & 7) ^ lrow;               // pre-swizzled source granule
  f32x4 acc[2][4] = {};

  // Per STAGE per thread: 2 A + 4 B = 6 gload16 -> vmcnt(6).
  // A: wave w stages rows [w*16, w*16+16); B: rows [w*32, w*32+32).
  #define STAGE(buf, kt)                                                        \
    { _Pragma("unroll")                                                         \
      for (int it = 0; it < 2; ++it){                                           \
        int r = wave*16 + it*8 + lrow;                                          \
        gload16((const void*)(Xb + (size_t)(m0 + r)*1024 + (kt)*64 + lg*8),     \
                (void*)&As_[buf][(wave*16 + it*8)*64]);                         \
      }                                                                         \
      _Pragma("unroll")                                                         \
      for (int it = 0; it < 4; ++it){                                           \
        int r = wave*32 + it*8 + lrow;                                          \
        gload16((const void*)(Tt + (size_t)(n0 + r)*1024 + (kt)*64 + lg*8),     \
                (void*)&Bs_[buf][(wave*32 + it*8)*64]);                         \
      } }

  STAGE(0, 0);
  STAGE(1, 1);
  #pragma unroll 1
  for (int kt = 0; kt < 16; ++kt){
    if (kt < 15) asm volatile("s_waitcnt vmcnt(6)" ::: "memory");
    else         asm volatile("s_waitcnt vmcnt(0)" ::: "memory");
    __builtin_amdgcn_s_barrier();
    const unsigned short* Ab = &As_[kt & 1][0];
    const unsigned short* Bb = &Bs_[kt & 1][0];
    #pragma unroll
    for (int kk = 0; kk < 2; ++kk){
      int gb = kk*4 + (lane >> 4);            // 16B granule within row
      bf16x8 af[2], bfr[4];
      #pragma unroll
      for (int m = 0; m < 2; ++m){
        int row = wm*32 + m*16 + (lane & 15);
        af[m] = *reinterpret_cast<const bf16x8*>((char*)Ab + row*128 + ((gb ^ (row & 7))*16));
      }
      #pragma unroll
      for (int n = 0; n < 4; ++n){
        int row = wn*64 + n*16 + (lane & 15);
        bfr[n] = *reinterpret_cast<const bf16x8*>((char*)Bb + row*128 + ((gb ^ (row & 7))*16));
      }
      #pragma unroll
      for (int m = 0; m < 2; ++m)
        #pragma unroll
        for (int n = 0; n < 4; ++n)
          acc[m][n] = __builtin_amdgcn_mfma_f32_16x16x32_bf16(af[m], bfr[n], acc[m][n], 0,0,0);
    }
    __builtin_amdgcn_s_barrier();             // all waves done reading buf kt&1
    if (kt < 14) STAGE(kt & 1, kt + 2);       // refill the buffer just drained
  }
  #undef STAGE

  #pragma unroll
  for (int m = 0; m < 2; ++m)
    #pragma unroll
    for (int n = 0; n < 4; ++n)
      #pragma unroll
      for (int r = 0; r < 4; ++r){
        int row = m0 + wm*32 + m*16 + (lane >> 4)*4 + r;
        int col = n0 + wn*64 + n*16 + (lane & 15);
        Y[(size_t)row*512 + col] = acc[m][n][r];
      }
}

extern "C" void kernel_launch(void* const* d_in, const int* in_sizes, int n_in,
                              void* d_out, int out_size, void* d_ws, size_t ws_size,
                              hipStream_t stream) {
  const float* x = (const float*)d_in[0];   // [16384][1024]
  const float* W = (const float*)d_in[1];   // [512][1024]
  const float* M = (const float*)d_in[2];   // [512][512]
  float* y = (float*)d_out;                 // [16384][512]

  float* Qa = (float*)d_ws;                               // 1 MB
  float* Qb = Qa + 512*512;                               // 1 MB
  float* Ra = Qb + 512*512;                               // 2 MB
  float* Rb = Ra + 512*1024;                              // 2 MB
  unsigned short* Tt = (unsigned short*)(Rb + 512*1024);  // 1 MB  [512][1024] bf16
  unsigned short* Xb = Tt + 512*1024;                     // 32 MB [16384][1024] bf16

  // 3 doublings (Tt = S_8^T W; absmax bit-identical to S_16, round 17).
  // ALL X conversion fused into step 1 only (one-time BW cost, ~15us,
  // partially hidden under step 1's latency-bound tiles).
  k_step<<<384, 256, 0, stream>>>(M,  W,  Qa, Ra, nullptr, x, Xb, 1, 0, 2048); // Rt2,Q2 + conv
  k_step<<<384, 256, 0, stream>>>(Qa, Ra, Qb, Rb, nullptr, x, Xb, 0, 0, 0);    // Rt4,Q4
  k_step<<<256, 256, 0, stream>>>(Qb, Rb, nullptr, nullptr, Tt, x, Xb, 0, 1, 0); // Tt=Rt8
  k_gemm18<<<1024, 256, 0, stream>>>(Xb, Tt, y);
}

// Round 19
// 58.587 us; speedup vs baseline: 1.2494x; 1.2494x over previous
//
#include <hip/hip_runtime.h>

typedef float f32x4 __attribute__((ext_vector_type(4)));
typedef __bf16 bf16x8 __attribute__((ext_vector_type(8)));
typedef unsigned short u16x4 __attribute__((ext_vector_type(4)));
typedef unsigned short u16x8 __attribute__((ext_vector_type(8)));

__device__ __forceinline__ unsigned short f2b(float f){
  return __builtin_bit_cast(unsigned short, (__bf16)f);
}
__device__ __forceinline__ float b2f(unsigned short u){
  union { unsigned x; float f; } v; v.x = ((unsigned)u) << 16; return v.f;
}
__device__ __forceinline__ void mfma3(f32x4& acc, bf16x8 ah, bf16x8 al, bf16x8 bh, bf16x8 bl){
  acc = __builtin_amdgcn_mfma_f32_16x16x32_bf16(ah, bh, acc, 0, 0, 0);
  acc = __builtin_amdgcn_mfma_f32_16x16x32_bf16(ah, bl, acc, 0, 0, 0);
  acc = __builtin_amdgcn_mfma_f32_16x16x32_bf16(al, bh, acc, 0, 0, 0);
}
__device__ __forceinline__ void gload16(const void* g, void* l){
  __builtin_amdgcn_global_load_lds((const __attribute__((address_space(1))) void*)g,
                                   (__attribute__((address_space(3))) void*)l, 16, 0, 0);
}

// ---------- chain staging loaders/writers (proven rounds 3-17) ----------
template<bool ATR>
__device__ __forceinline__ void loadA(const float* __restrict__ A, int i0, int k0,
                                      int tid, float* aR){
  if (ATR){
    int r32 = tid & 31, kg = tid >> 5;
    #pragma unroll
    for (int q = 0; q < 8; ++q)
      aR[q] = -A[(k0 + kg*8 + q)*512 + i0 + r32];
  } else {
    #pragma unroll
    for (int j = 0; j < 2; ++j){
      int p = tid + j*256;
      int row = p >> 4, kq = p & 15;
      f32x4 v = *reinterpret_cast<const f32x4*>(A + (i0+row)*512 + k0 + kq*4);
      #pragma unroll
      for (int e = 0; e < 4; ++e) aR[j*4+e] = v[e];
    }
  }
}
template<bool ATR>
__device__ __forceinline__ void writeA(const float* aR, int tid,
                                       unsigned short* Ah, unsigned short* Al){
  if (ATR){
    int r32 = tid & 31, kg = tid >> 5;
    #pragma unroll
    for (int q4 = 0; q4 < 2; ++q4){
      u16x4 hi, lo;
      #pragma unroll
      for (int e = 0; e < 4; ++e){
        float f = aR[q4*4+e];
        unsigned short h = f2b(f);
        hi[e] = h; lo[e] = f2b(f - b2f(h));
      }
      int off = r32*128 + (((kg*8 + q4*4)*2) ^ ((r32 & 7) << 4));
      *reinterpret_cast<u16x4*>((char*)Ah + off) = hi;
      *reinterpret_cast<u16x4*>((char*)Al + off) = lo;
    }
  } else {
    #pragma unroll
    for (int j = 0; j < 2; ++j){
      int p = tid + j*256;
      int row = p >> 4, kq = p & 15;
      u16x4 hi, lo;
      #pragma unroll
      for (int e = 0; e < 4; ++e){
        float f = aR[j*4+e];
        unsigned short h = f2b(f);
        hi[e] = h; lo[e] = f2b(f - b2f(h));
      }
      int off = row*128 + ((kq*8) ^ ((row & 7) << 4));
      *reinterpret_cast<u16x4*>((char*)Ah + off) = hi;
      *reinterpret_cast<u16x4*>((char*)Al + off) = lo;
    }
  }
}
template<bool BROWM>
__device__ __forceinline__ void loadB(const float* __restrict__ B, int j0, int k0,
                                      int sb, int tid, float* bR){
  if (BROWM){
    #pragma unroll
    for (int j = 0; j < 4; ++j){
      int p = tid + j*256;
      int n = p >> 4, kq = p & 15;
      f32x4 v = *reinterpret_cast<const f32x4*>(B + (j0+n)*512 + k0 + kq*4);
      #pragma unroll
      for (int e = 0; e < 4; ++e) bR[j*4+e] = -v[e];
    }
  } else {
    int n = tid & 63, kg = tid >> 6;
    #pragma unroll
    for (int q = 0; q < 16; ++q)
      bR[q] = B[(k0 + kg*16 + q)*sb + j0 + n];
  }
}
template<bool BROWM>
__device__ __forceinline__ void writeB(const float* bR, int tid,
                                       unsigned short* Bh, unsigned short* Bl){
  if (BROWM){
    #pragma unroll
    for (int j = 0; j < 4; ++j){
      int p = tid + j*256;
      int n = p >> 4, kq = p & 15;
      u16x4 hi, lo;
      #pragma unroll
      for (int e = 0; e < 4; ++e){
        float f = bR[j*4+e];
        unsigned short h = f2b(f);
        hi[e] = h; lo[e] = f2b(f - b2f(h));
      }
      int off = n*128 + ((kq*8) ^ ((n & 7) << 4));
      *reinterpret_cast<u16x4*>((char*)Bh + off) = hi;
      *reinterpret_cast<u16x4*>((char*)Bl + off) = lo;
    }
  } else {
    int n = tid & 63, kg = tid >> 6;
    #pragma unroll
    for (int q4 = 0; q4 < 4; ++q4){
      u16x4 hi, lo;
      #pragma unroll
      for (int e = 0; e < 4; ++e){
        float f = bR[q4*4+e];
        unsigned short h = f2b(f);
        hi[e] = h; lo[e] = f2b(f - b2f(h));
      }
      int off = n*128 + (((kg*16 + q4*4)*2) ^ ((n & 7) << 4));
      *reinterpret_cast<u16x4*>((char*)Bh + off) = hi;
      *reinterpret_cast<u16x4*>((char*)Bl + off) = lo;
    }
  }
}

// One 32x64 tile of C = [D +] A*B over K=512, split-bf16, 3-deep reg pipeline.
template<bool ATR, bool BROWM, bool HASD, bool BFOUT>
__device__ __forceinline__ void gtile(
    const float* __restrict__ A, const float* __restrict__ B,
    const float* __restrict__ D, float* __restrict__ Cf,
    unsigned short* __restrict__ Cb, int i0, int j0, int sb, int so,
    unsigned short* Ah, unsigned short* Al,
    unsigned short* Bh, unsigned short* Bl, int tid)
{
  int lane = tid & 63, wave = tid >> 6;
  int wm = wave >> 1, wn = wave & 1;
  f32x4 acc[2] = {};
  float aR0[8], bR0[16], aR1[8], bR1[16];
  loadA<ATR>(A, i0, 0, tid, aR0);
  loadB<BROWM>(B, j0, 0, sb, tid, bR0);
  loadA<ATR>(A, i0, 64, tid, aR1);
  loadB<BROWM>(B, j0, 64, sb, tid, bR1);

#define CHAIN_MFMA_PHASE                                                   \
    { _Pragma("unroll")                                                    \
      for (int kk = 0; kk < 2; ++kk){                                      \
        int kb = (kk*32 + (lane >> 4)*8) * 2;                              \
        int arow = wm*16 + (lane & 15);                                    \
        int aoff = arow*128 + (kb ^ ((arow & 7) << 4));                    \
        bf16x8 ah = *reinterpret_cast<const bf16x8*>((char*)Ah + aoff);    \
        bf16x8 al = *reinterpret_cast<const bf16x8*>((char*)Al + aoff);    \
        _Pragma("unroll")                                                  \
        for (int n = 0; n < 2; ++n){                                       \
          int brow = wn*32 + n*16 + (lane & 15);                           \
          int boff = brow*128 + (kb ^ ((brow & 7) << 4));                  \
          bf16x8 bh = *reinterpret_cast<const bf16x8*>((char*)Bh + boff);  \
          bf16x8 bl = *reinterpret_cast<const bf16x8*>((char*)Bl + boff);  \
          mfma3(acc[n], ah, al, bh, bl);                                   \
        }                                                                  \
      } }

  #pragma unroll 1
  for (int k0 = 0; k0 < 512; k0 += 128){
    writeA<ATR>(aR0, tid, Ah, Al);
    writeB<BROWM>(bR0, tid, Bh, Bl);
    __syncthreads();
    if (k0 + 128 < 512){
      loadA<ATR>(A, i0, k0 + 128, tid, aR0);
      loadB<BROWM>(B, j0, k0 + 128, sb, tid, bR0);
    }
    CHAIN_MFMA_PHASE
    __syncthreads();
    writeA<ATR>(aR1, tid, Ah, Al);
    writeB<BROWM>(bR1, tid, Bh, Bl);
    __syncthreads();
    if (k0 + 192 < 512){
      loadA<ATR>(A, i0, k0 + 192, tid, aR1);
      loadB<BROWM>(B, j0, k0 + 192, sb, tid, bR1);
    }
    CHAIN_MFMA_PHASE
    __syncthreads();
  }
#undef CHAIN_MFMA_PHASE

  #pragma unroll
  for (int n = 0; n < 2; ++n)
    #pragma unroll
    for (int r = 0; r < 4; ++r){
      int i = i0 + wm*16 + (lane >> 4)*4 + r;
      int j = j0 + wn*32 + n*16 + (lane & 15);
      float v = acc[n][r];
      if (HASD) v += D[i*so + j];
      if (BFOUT) Cb[i*so + j] = f2b(v);
      else       Cf[i*so + j] = v;
    }
}

// Doubling step: Rt_2n = Rt_n + Q_n*Rt_n (256 tiles), Q_2n = Q_n^2 (128 tiles).
__global__ __launch_bounds__(256, 2) void k_step(
    const float* __restrict__ Q, const float* __restrict__ R,
    float* __restrict__ Qout, float* __restrict__ Rout,
    unsigned short* __restrict__ Tout, int first, int last)
{
  __shared__ unsigned short Ah[32*64], Al[32*64], Bh[64*64], Bl[64*64];
  int tid = threadIdx.x, bid = blockIdx.x;
  if (bid < 256){
    int i0 = (bid >> 4) * 32, j0 = (bid & 15) * 64;
    if (last)
      gtile<false,false,true ,true >(Q, R, R, nullptr, Tout, i0, j0, 1024, 1024, Ah,Al,Bh,Bl, tid);
    else if (first)
      gtile<true ,false,true ,false>(Q, R, R, Rout, nullptr, i0, j0, 1024, 1024, Ah,Al,Bh,Bl, tid);
    else
      gtile<false,false,true ,false>(Q, R, R, Rout, nullptr, i0, j0, 1024, 1024, Ah,Al,Bh,Bl, tid);
  } else {
    int t = bid - 256;
    int i0 = (t >> 3) * 32, j0 = (t & 7) * 64;
    if (first)
      gtile<true ,true ,false,false>(Q, Q, nullptr, Qout, nullptr, i0, j0, 512, 512, Ah,Al,Bh,Bl, tid);
    else
      gtile<false,false,false,false>(Q, Q, nullptr, Qout, nullptr, i0, j0, 512, 512, Ah,Al,Bh,Bl, tid);
  }
}

// Y[16384][512] = X[16384][1024](f32) * Tt^T (bf16).  (R13/R17-proven champion)
// BM=BN=128, BK=64, SINGLE-buffered 48 KB (A f32 32K + B bf16 16K).
// A: slot = g ^ (row&15) (balanced 8/bank); B: slot = g ^ (row&7) (0-conflict).
__global__ __launch_bounds__(256, 3) void k_gemm13(const float* __restrict__ X,
                                                   const unsigned short* __restrict__ Tt,
                                                   float* __restrict__ Y)
{
  __shared__ float          As_[128*64];   // 32 KB
  __shared__ unsigned short Bs_[128*64];   // 16 KB
  int tid = threadIdx.x;
  int lane = tid & 63, wave = tid >> 6;
  int wm = wave >> 1, wn = wave & 1;
  int bid = blockIdx.x;
  int wg = (bid & 7) * 64 + (bid >> 3);    // XCD chunks (512 % 8 == 0)
  int m0 = (wg >> 2) * 128;
  int n0 = (wg & 3) * 128;                 // n fastest: X panel L2 reuse

  int lrowA = lane >> 4, slotA = lane & 15;   // A: 4 rows / issue
  int lrowB = lane >> 3, slotB = lane & 7;    // B: 8 rows / issue

  f32x4 acc[4][4] = {};

  #pragma unroll 1
  for (int kt = 0; kt < 16; ++kt){
    #pragma unroll
    for (int it = 0; it < 8; ++it){
      int r = wave*32 + it*4 + lrowA;
      int gsrc = slotA ^ (r & 15);
      gload16((const void*)(X + (size_t)(m0 + r)*1024 + kt*64 + gsrc*4),
              (void*)&As_[(wave*32 + it*4)*64]);
    }
    #pragma unroll
    for (int it = 0; it < 4; ++it){
      int r = wave*32 + it*8 + lrowB;
      int gsrc = slotB ^ (r & 7);
      gload16((const void*)(Tt + (size_t)(n0 + r)*1024 + kt*64 + gsrc*8),
              (void*)&Bs_[(wave*32 + it*8)*64]);
    }
    asm volatile("s_waitcnt vmcnt(0)" ::: "memory");
    __builtin_amdgcn_s_barrier();
    #pragma unroll
    for (int kk = 0; kk < 2; ++kk){
      int g0 = kk*8 + (lane >> 4)*2;     // f32 granule pair base
      int gb = kk*4 + (lane >> 4);       // bf16 granule
      bf16x8 af[4], bfr[4];
      #pragma unroll
      for (int m = 0; m < 4; ++m){
        int row = wm*64 + m*16 + (lane & 15);
        const float* rp = As_ + row*64;
        f32x4 v0 = *reinterpret_cast<const f32x4*>(rp + ((g0    ) ^ (row & 15))*4);
        f32x4 v1 = *reinterpret_cast<const f32x4*>(rp + ((g0 + 1) ^ (row & 15))*4);
        bf16x8 a;
        #pragma unroll
        for (int e = 0; e < 4; ++e){ a[e] = (__bf16)v0[e]; a[4+e] = (__bf16)v1[e]; }
        af[m] = a;
      }
      #pragma unroll
      for (int n = 0; n < 4; ++n){
        int row = wn*64 + n*16 + (lane & 15);
        bfr[n] = *reinterpret_cast<const bf16x8*>(Bs_ + row*64 + (gb ^ (row & 7))*8);
      }
      #pragma unroll
      for (int m = 0; m < 4; ++m)
        #pragma unroll
        for (int n = 0; n < 4; ++n)
          acc[m][n] = __builtin_amdgcn_mfma_f32_16x16x32_bf16(af[m], bfr[n], acc[m][n], 0,0,0);
    }
    __builtin_amdgcn_s_barrier();        // all waves done before restage
  }

  #pragma unroll
  for (int m = 0; m < 4; ++m)
    #pragma unroll
    for (int n = 0; n < 4; ++n)
      #pragma unroll
      for (int r = 0; r < 4; ++r){
        int row = m0 + wm*64 + m*16 + (lane >> 4)*4 + r;
        int col = n0 + wn*64 + n*16 + (lane & 15);
        Y[(size_t)row*512 + col] = acc[m][n][r];
      }
}

extern "C" void kernel_launch(void* const* d_in, const int* in_sizes, int n_in,
                              void* d_out, int out_size, void* d_ws, size_t ws_size,
                              hipStream_t stream) {
  const float* x = (const float*)d_in[0];   // [16384][1024]
  const float* W = (const float*)d_in[1];   // [512][1024]
  const float* M = (const float*)d_in[2];   // [512][512]
  float* y = (float*)d_out;                 // [16384][512]

  float* Qa = (float*)d_ws;                               // 1 MB
  float* Qb = Qa + 512*512;                               // 1 MB
  float* Ra = Qb + 512*512;                               // 2 MB
  float* Rb = Ra + 512*1024;                              // 2 MB
  unsigned short* Tt = (unsigned short*)(Rb + 512*1024);  // 1 MB  [512][1024] bf16

  // 3 doublings: Tt = S_8^T W (absmax bit-identical to S_16/S_32/S_128; R17).
  k_step<<<384, 256, 0, stream>>>(M,  W,  Qa, Ra, nullptr, 1, 0);     // Rt2,  Q2
  k_step<<<384, 256, 0, stream>>>(Qa, Ra, Qb, Rb, nullptr, 0, 0);     // Rt4,  Q4
  k_step<<<256, 256, 0, stream>>>(Qb, Rb, nullptr, nullptr, Tt, 0, 1);// Tt = Rt8 (bf16)
  k_gemm13<<<512, 256, 0, stream>>>(x, Tt, y);
}